// Round 19
// baseline (191.657 us; speedup 1.0000x reference)
//
#include <hip/hip_runtime.h>
#include <math.h>

typedef short  short8  __attribute__((ext_vector_type(8)));
typedef short  short4v __attribute__((ext_vector_type(4)));
typedef float  f32x4   __attribute__((ext_vector_type(4)));

constexpr int D   = 1024;   // d_in = d_g
constexpr int K   = 512;    // codebook size
constexpr int BM  = 32;     // rows per block (vq_main) -> grid 512, 2 blocks/CU
constexpr int KP  = 256;    // k-panel (f32 elements)
constexpr int ROWS = 16384;
// Single-product bf16 noise on the top-2 gap: sigma ~= 1.6e-3 (raw z, |z|~32).
// GAP_T = 2e-2 ~= 12.5 sigma -> miss probability ~0; flags ~6% of rows (~1000),
// all recomputed exactly by vq_rescue (one wave per flagged row).
constexpr float GAP_T = 2e-2f;

__device__ __forceinline__ unsigned short f2bf(float f) {
    unsigned u = __float_as_uint(f);
    u += 0x7FFFu + ((u >> 16) & 1u);          // round-to-nearest-even
    return (unsigned short)(u >> 16);
}
__device__ __forceinline__ float bf2f(unsigned short h) {
    return __uint_as_float(((unsigned)h) << 16);
}
// convert one float4 -> 4 bf16 (hi only) and store 8B to LDS
__device__ __forceinline__ void cvt_write_hi(const float4 v, unsigned char* dh) {
    const short4v hv = { (short)f2bf(v.x), (short)f2bf(v.y),
                         (short)f2bf(v.z), (short)f2bf(v.w) };
    *reinterpret_cast<short4v*>(dh) = hv;
}

// ---------------------------------------------------------------------------
// Kernel A: normalize codebook rows; emit MFMA-fragment-packed bf16 (hi only)
// + TRANSPOSED f32 copy cft[d][k] (exact, for rescue). Zeroes rcnt.
// ---------------------------------------------------------------------------
__global__ __launch_bounds__(256)
void prep_codebook(const float* __restrict__ cb, unsigned short* __restrict__ cbp,
                   float* __restrict__ cft, int* __restrict__ rcnt) {
    if (blockIdx.x == 0 && threadIdx.x == 0) rcnt[0] = 0;
    const int n = blockIdx.x, tid = threadIdx.x;
    const float4 v = reinterpret_cast<const float4*>(cb + (size_t)n * D)[tid];
    float ss = v.x*v.x + v.y*v.y + v.z*v.z + v.w*v.w;
#pragma unroll
    for (int off = 32; off > 0; off >>= 1) ss += __shfl_down(ss, off);
    __shared__ float wss[4];
    if ((tid & 63) == 0) wss[tid >> 6] = ss;
    __syncthreads();
    const float tot   = wss[0] + wss[1] + wss[2] + wss[3];
    const float scale = 1.0f / fmaxf(sqrtf(tot), 1e-12f);
    float f[4] = { v.x*scale, v.y*scale, v.z*scale, v.w*scale };
    const int d0 = tid * 4;
#pragma unroll
    for (int i = 0; i < 4; ++i) cft[(size_t)(d0 + i) * K + n] = f[i];

    const short4v hv = { (short)f2bf(f[0]), (short)f2bf(f[1]),
                         (short)f2bf(f[2]), (short)f2bf(f[3]) };
    const int ct   = n >> 4;           // code tile 0..31
    const int lr   = n & 15;
    const int ks_g = tid >> 3;         // k-step 0..31
    const int lg   = (tid >> 1) & 3;
    const int half = tid & 1;
    const size_t fbase = (size_t)(ct * 32 + ks_g) * 1024;   // bytes
    unsigned char* base = (unsigned char*)cbp;
    *reinterpret_cast<short4v*>(base + fbase + (lg * 16 + lr) * 16 + half * 8) = hv;
}

// ---------------------------------------------------------------------------
// Kernel B (FUSED): single-product bf16 MFMA GEMM + top-2 + epilogue.
// BM=32 rows x 512 codes per block, grid 512, 8 waves, 2 blocks/CU
// (32 KB LDS dbuf). Per wave: m=2 x nt=4; per k-step: 2 LDS reads +
// 4 B-loads + 8 MFMA. Flagged rows (gap < GAP_T) recomputed by vq_rescue.
// ---------------------------------------------------------------------------
__global__ __launch_bounds__(512)
void vq_main(const float* __restrict__ z, const float* __restrict__ tgt,
             const unsigned short* __restrict__ cbp, const float* __restrict__ E,
             float* __restrict__ out, int* __restrict__ rlist,
             int* __restrict__ rcnt) {
    __shared__ alignas(16) unsigned char LDS[2][BM * KP * 2];  // 2 x 16 KB (hi)

    const int tid = threadIdx.x;
    const int r0  = blockIdx.x * BM;
    const int l   = tid & 63;
    const int wv  = tid >> 6;        // 0..7
    const int lr  = l & 15;
    const int lg  = l >> 4;

    f32x4 acc[2][4];
#pragma unroll
    for (int m = 0; m < 2; ++m)
#pragma unroll
        for (int nt = 0; nt < 4; ++nt) acc[m][nt] = (f32x4){0.f, 0.f, 0.f, 0.f};

    const int aswz = (lr & 7) << 4;
    const unsigned char* bbase = (const unsigned char*)cbp + l * 16;
#define BFRAG(fi) (*reinterpret_cast<const short8*>(bbase + (unsigned)(fi) * 1024u))

    // staging decomposition: thread covers rows row0+8c (c=0..3) at f4-col c4
    const int c4    = tid & 63;
    const int row0  = tid >> 6;          // 0..7
    const int swz_w = (row0 & 7) << 4;
    const float* zbase = z + (size_t)(r0 + row0) * D + c4 * 4;

    // prologue: panel 0 -> buf 0
    {
        float4 zn[4];
#pragma unroll
        for (int c = 0; c < 4; ++c)
            zn[c] = *reinterpret_cast<const float4*>(zbase + (size_t)(8 * c) * D);
#pragma unroll
        for (int c = 0; c < 4; ++c) {
            const int ad = ((row0 + 8 * c) * 512 + c4 * 8) ^ swz_w;
            cvt_write_hi(zn[c], &LDS[0][ad]);
        }
    }

#pragma unroll 1
    for (int p = 0; p < 4; ++p) {
        __syncthreads();
        unsigned char* Ah  = &LDS[p & 1][0];
        unsigned char* Ahn = &LDS[(p + 1) & 1][0];

        // (a) issue next panel's global z loads early (T14)
        float4 zn[4];
        if (p < 3) {
#pragma unroll
            for (int c = 0; c < 4; ++c)
                zn[c] = *reinterpret_cast<const float4*>(
                    zbase + (size_t)(8 * c) * D + (p + 1) * KP);
        }

        // (b) MFMA: 8 k-steps of 32; B register pipeline one step ahead
        const int fp0 = wv * 128 + p * 8;    // fragment index base
        short8 b0[4], b1[4];
#pragma unroll
        for (int nt = 0; nt < 4; ++nt) b0[nt] = BFRAG(fp0 + nt * 32);
#pragma unroll 2
        for (int ks = 0; ks < 8; ++ks) {
            if (ks < 7) {
#pragma unroll
                for (int nt = 0; nt < 4; ++nt)
                    b1[nt] = BFRAG(fp0 + nt * 32 + ks + 1);
            }
            short8 ah[2];
#pragma unroll
            for (int m = 0; m < 2; ++m) {
                const int ad = ((m * 16 + lr) * 512 + lg * 16 + ks * 64) ^ aswz;
                ah[m] = *reinterpret_cast<const short8*>(Ah + ad);
            }
#pragma unroll
            for (int nt = 0; nt < 4; ++nt)
#pragma unroll
                for (int m = 0; m < 2; ++m)
                    acc[m][nt] = __builtin_amdgcn_mfma_f32_16x16x32_bf16(
                        ah[m], b0[nt], acc[m][nt], 0, 0, 0);
#pragma unroll
            for (int nt = 0; nt < 4; ++nt) b0[nt] = b1[nt];
        }

        // (c) convert + write next panel into the other buffer (VALU tail)
        if (p < 3) {
#pragma unroll
            for (int c = 0; c < 4; ++c) {
                const int ad = ((row0 + 8 * c) * 512 + c4 * 8) ^ swz_w;
                cvt_write_hi(zn[c], Ahn + ad);
            }
        }
    }
#undef BFRAG

    // ---- A-panels done: alias reduction arrays onto LDS[1] (post-barrier) --
    __syncthreads();
    float* cv1     = (float*)&LDS[1][0];       // [8][32]
    float* cv2     = (float*)&LDS[1][1024];    // [8][32]
    int*   ci1     = (int*)  &LDS[1][2048];    // [8][32]
    int*   bestk_s = (int*)  &LDS[1][3072];    // [32]

    // ---- top-2 per row: nt scan, 16-lane butterfly, wave merge ----
    // acc[m][nt][r] = logits[row = m*16 + lg*4 + r][code = wv*64 + nt*16 + lr]
#pragma unroll
    for (int m = 0; m < 2; ++m)
#pragma unroll
        for (int r = 0; r < 4; ++r) {
            float v1 = acc[m][0][r];
            int   i1 = wv * 64 + lr;
            float v2 = -INFINITY;
#pragma unroll
            for (int nt = 1; nt < 4; ++nt) {
                const float v = acc[m][nt][r];
                const int   n = wv * 64 + nt * 16 + lr;
                if (v > v1) { v2 = v1; v1 = v; i1 = n; }
                else        { v2 = fmaxf(v2, v); }
            }
#pragma unroll
            for (int msk = 1; msk < 16; msk <<= 1) {
                const float ov1 = __shfl_xor(v1, msk);
                const float ov2 = __shfl_xor(v2, msk);
                const int   oi1 = __shfl_xor(i1, msk);
                if (ov1 > v1 || (ov1 == v1 && oi1 < i1)) { v2 = fmaxf(v1, ov2); v1 = ov1; i1 = oi1; }
                else                                     { v2 = fmaxf(v2, ov1); }
            }
            if (lr == 0) {
                const int row = m * 16 + lg * 4 + r;
                cv1[wv * BM + row] = v1; cv2[wv * BM + row] = v2; ci1[wv * BM + row] = i1;
            }
        }
    __syncthreads();
    if (tid < BM) {
        float v1 = cv1[tid], v2 = cv2[tid];
        int   i1 = ci1[tid];
        for (int w = 1; w < 8; ++w) {
            const float a1 = cv1[w * BM + tid], a2 = cv2[w * BM + tid];
            const int   b1 = ci1[w * BM + tid];
            if (a1 > v1 || (a1 == v1 && b1 < i1)) { v2 = fmaxf(v1, a2); v1 = a1; i1 = b1; }
            else                                  { v2 = fmaxf(v2, a1); }
        }
        bestk_s[tid] = i1;
        if (v1 - v2 < GAP_T) {
            const int pos = atomicAdd(rcnt, 1);
            rlist[pos] = r0 + tid;
        }
    }
    __syncthreads();

    // ---- fused epilogue: out = target * (1 + E[best]) for the 32 rows ----
    const int erow = tid >> 4;           // 0..31
    const int ecol = tid & 15;           // float4 lane within 16-thread group
    const int bi   = bestk_s[erow];
    const float4* trow = reinterpret_cast<const float4*>(tgt + (size_t)(r0 + erow) * D);
    const float4* eptr = reinterpret_cast<const float4*>(E + (size_t)bi * D);
    float4*       orow = reinterpret_cast<float4*>(out + (size_t)(r0 + erow) * D);
#pragma unroll 4
    for (int it = 0; it < 16; ++it) {
        const int c = ecol + it * 16;    // 0..255
        const float4 tv = trow[c];
        const float4 ev = eptr[c];
        float4 o;
        o.x = tv.x * (1.0f + ev.x);
        o.y = tv.y * (1.0f + ev.y);
        o.z = tv.z * (1.0f + ev.z);
        o.w = tv.w * (1.0f + ev.w);
        orow[c] = o;
    }
}

// ---------------------------------------------------------------------------
// Kernel C: exact f32 rescue. ONE WAVE PER FLAGGED ROW, 8 rows per block
// (512 threads = 8 waves, rows staged in 32 KB LDS). Wave w sweeps the whole
// codebook for row w: lane owns 8 codes -> two coalesced float4 ct loads per
// d (8 waves share the stream via L1); zs read as float4 per 4 d. No
// cross-wave merge: wave-local shuffle argmax, wave rewrites its own row.
// Tail replicates rlist[cnt-1] (duplicate rows write identical data).
// ---------------------------------------------------------------------------
__global__ __launch_bounds__(512)
void vq_rescue(const float* __restrict__ z, const float* __restrict__ cft,
               const float* __restrict__ tgt, const float* __restrict__ E,
               const int* __restrict__ rlist, const int* __restrict__ rcnt,
               float* __restrict__ out) {
    const int cnt = rcnt[0];
    const int tid = threadIdx.x;
    const int l   = tid & 63;
    const int wv  = tid >> 6;        // 0..7
    __shared__ float zs[8][D];       // 32 KB

    const float4* ctb = reinterpret_cast<const float4*>(cft) + l * 2;  // [d][128 f4]

    for (int i0 = blockIdx.x * 8; i0 < cnt; i0 += gridDim.x * 8) {
        __syncthreads();             // protect zs reuse across iterations
        // stage 8 rows: 2048 float4 over 512 threads -> 4 each
#pragma unroll
        for (int j = 0; j < 4; ++j) {
            const int f   = tid + 512 * j;
            const int r   = f >> 8;          // 0..7
            const int c   = f & 255;
            const int row = rlist[min(i0 + r, cnt - 1)];
            reinterpret_cast<float4*>(&zs[r][0])[c] =
                reinterpret_cast<const float4*>(z + (size_t)row * D)[c];
        }
        __syncthreads();

        const int myrow = rlist[min(i0 + wv, cnt - 1)];

        float s[8];
#pragma unroll
        for (int j = 0; j < 8; ++j) s[j] = 0.f;

        const float4* zrow = reinterpret_cast<const float4*>(&zs[wv][0]);
#pragma unroll 2
        for (int d4 = 0; d4 < D / 4; ++d4) {
            const float4 zv = zrow[d4];
#pragma unroll
            for (int e = 0; e < 4; ++e) {
                const int d = d4 * 4 + e;
                const float4 c0 = ctb[(size_t)d * 128];
                const float4 c1 = ctb[(size_t)d * 128 + 1];
                const float a = (e == 0) ? zv.x : (e == 1) ? zv.y : (e == 2) ? zv.z : zv.w;
                s[0] = fmaf(a, c0.x, s[0]); s[1] = fmaf(a, c0.y, s[1]);
                s[2] = fmaf(a, c0.z, s[2]); s[3] = fmaf(a, c0.w, s[3]);
                s[4] = fmaf(a, c1.x, s[4]); s[5] = fmaf(a, c1.y, s[5]);
                s[6] = fmaf(a, c1.z, s[6]); s[7] = fmaf(a, c1.w, s[7]);
            }
        }

        // lane-local argmax over its 8 codes (ascending -> first-index ties)
        float bv = s[0];
        int   bi = l * 8;
#pragma unroll
        for (int j = 1; j < 8; ++j)
            if (s[j] > bv) { bv = s[j]; bi = l * 8 + j; }
        // cross-lane reduce (lower index wins ties)
#pragma unroll
        for (int off = 32; off > 0; off >>= 1) {
            const float ov = __shfl_down(bv, off);
            const int   oi = __shfl_down(bi, off);
            if (ov > bv || (ov == bv && oi < bi)) { bv = ov; bi = oi; }
        }
        const int best = __shfl(bi, 0);

        // rewrite this wave's output row (256 f4 over 64 lanes -> 4 each)
        const float4* trow = reinterpret_cast<const float4*>(tgt + (size_t)myrow * D);
        const float4* eptr = reinterpret_cast<const float4*>(E + (size_t)best * D);
        float4*       orow = reinterpret_cast<float4*>(out + (size_t)myrow * D);
#pragma unroll
        for (int j = 0; j < 4; ++j) {
            const int c = l + 64 * j;
            const float4 tv = trow[c];
            const float4 ev = eptr[c];
            float4 o;
            o.x = tv.x * (1.0f + ev.x);
            o.y = tv.y * (1.0f + ev.y);
            o.z = tv.z * (1.0f + ev.z);
            o.w = tv.w * (1.0f + ev.w);
            orow[c] = o;
        }
    }
}

extern "C" void kernel_launch(void* const* d_in, const int* in_sizes, int n_in,
                              void* d_out, int out_size, void* d_ws, size_t ws_size,
                              hipStream_t stream) {
    const float* z        = (const float*)d_in[0];
    const float* target   = (const float*)d_in[1];
    const float* codebook = (const float*)d_in[2];
    const float* E        = (const float*)d_in[3];
    float* out = (float*)d_out;

    unsigned short* cbp   = (unsigned short*)d_ws;              // 1 MB packed hi
    float*          cft   = (float*)(cbp + (size_t)K * D);      // 2 MB f32 transposed
    int*            rlist = (int*)(cft + (size_t)K * D);        // 64 KB
    int*            rcnt  = rlist + ROWS;                       // 4 B

    const int rows = in_sizes[0] / D;                           // 16384
    hipLaunchKernelGGL(prep_codebook, dim3(K), dim3(256), 0, stream,
                       codebook, cbp, cft, rcnt);
    hipLaunchKernelGGL(vq_main, dim3(rows / BM), dim3(512), 0, stream,
                       z, target, cbp, E, out, rlist, rcnt);
    hipLaunchKernelGGL(vq_rescue, dim3(256), dim3(512), 0, stream,
                       z, cft, target, E, rlist, rcnt, out);
}

// Round 20
// 140.946 us; speedup vs baseline: 1.3598x; 1.3598x over previous
//
#include <hip/hip_runtime.h>
#include <math.h>

typedef short  short8  __attribute__((ext_vector_type(8)));
typedef short  short4v __attribute__((ext_vector_type(4)));
typedef float  f32x4   __attribute__((ext_vector_type(4)));

constexpr int D   = 1024;   // d_in = d_g
constexpr int K   = 512;    // codebook size
constexpr int BM  = 32;     // rows per block (vq_main) -> grid 512, 2 blocks/CU
constexpr int KP  = 256;    // k-panel (f32 elements)
constexpr int ROWS = 16384;
// 3-product split-bf16 noise vs numpy f32: sigma ~1-3e-6 (zl*cl residual +
// f32 accumulation-order). GAP_T = 2e-3 is several hundred sigma (proven in
// r14/r15, absmax 0.0); flags ~160 rows, recomputed exactly by vq_rescue.
constexpr float GAP_T = 2e-3f;

__device__ __forceinline__ unsigned short f2bf(float f) {
    unsigned u = __float_as_uint(f);
    u += 0x7FFFu + ((u >> 16) & 1u);          // round-to-nearest-even
    return (unsigned short)(u >> 16);
}
__device__ __forceinline__ float bf2f(unsigned short h) {
    return __uint_as_float(((unsigned)h) << 16);
}
// convert one float4 -> bf16 hi/lo 8B chunks and store to LDS
__device__ __forceinline__ void cvt_write(const float4 v,
                                          unsigned char* dh, unsigned char* dl) {
    const unsigned short h0 = f2bf(v.x), h1 = f2bf(v.y), h2 = f2bf(v.z), h3 = f2bf(v.w);
    const short4v hv = { (short)h0, (short)h1, (short)h2, (short)h3 };
    const short4v lv = { (short)f2bf(v.x - bf2f(h0)), (short)f2bf(v.y - bf2f(h1)),
                         (short)f2bf(v.z - bf2f(h2)), (short)f2bf(v.w - bf2f(h3)) };
    *reinterpret_cast<short4v*>(dh) = hv;
    *reinterpret_cast<short4v*>(dl) = lv;
}

// ---------------------------------------------------------------------------
// Kernel A: normalize codebook rows; emit MFMA-fragment-packed bf16 hi/lo
// (cbp) + TRANSPOSED f32 copy cft[d][k] (exact, for rescue). Zeroes rcnt.
// ---------------------------------------------------------------------------
__global__ __launch_bounds__(256)
void prep_codebook(const float* __restrict__ cb, unsigned short* __restrict__ cbp,
                   float* __restrict__ cft, int* __restrict__ rcnt) {
    if (blockIdx.x == 0 && threadIdx.x == 0) rcnt[0] = 0;
    const int n = blockIdx.x, tid = threadIdx.x;
    const float4 v = reinterpret_cast<const float4*>(cb + (size_t)n * D)[tid];
    float ss = v.x*v.x + v.y*v.y + v.z*v.z + v.w*v.w;
#pragma unroll
    for (int off = 32; off > 0; off >>= 1) ss += __shfl_down(ss, off);
    __shared__ float wss[4];
    if ((tid & 63) == 0) wss[tid >> 6] = ss;
    __syncthreads();
    const float tot   = wss[0] + wss[1] + wss[2] + wss[3];
    const float scale = 1.0f / fmaxf(sqrtf(tot), 1e-12f);
    float f[4] = { v.x*scale, v.y*scale, v.z*scale, v.w*scale };
    const int d0 = tid * 4;
#pragma unroll
    for (int i = 0; i < 4; ++i) cft[(size_t)(d0 + i) * K + n] = f[i];

    unsigned short h[4], lo[4];
#pragma unroll
    for (int i = 0; i < 4; ++i) { h[i] = f2bf(f[i]); lo[i] = f2bf(f[i] - bf2f(h[i])); }
    short4v hv = { (short)h[0], (short)h[1], (short)h[2], (short)h[3] };
    short4v lv = { (short)lo[0], (short)lo[1], (short)lo[2], (short)lo[3] };

    const int nt_g = n >> 4;           // code tile 0..31
    const int lr   = n & 15;
    const int ks_g = tid >> 3;         // k-step 0..31
    const int lg   = (tid >> 1) & 3;
    const int half = tid & 1;
    const size_t fbase = ((size_t)(nt_g * 32 + ks_g) * 2) * 1024;   // bytes
    unsigned char* base = (unsigned char*)cbp;
    *reinterpret_cast<short4v*>(base + fbase + (lg * 16 + lr) * 16 + half * 8) = hv;
    *reinterpret_cast<short4v*>(base + fbase + 1024 + (lg * 16 + lr) * 16 + half * 8) = lv;
}

// ---------------------------------------------------------------------------
// Kernel B (FUSED): 3-product split-bf16 MFMA GEMM + top-2 + epilogue.
// BM=32 rows x 512 codes per block, grid 512, 8 waves, 2 blocks/CU
// (64 KB LDS dbuf). Plain __launch_bounds__(512): this is the configuration
// that keeps VGPR ~112-116 and the B register pipeline alive (r10/r14);
// waves_per_eu attributes squeezed VGPR to 64 and cost 1.6x (r15).
// One block's epilogue/staging memory traffic fills the co-resident block's
// MFMA-stall slots. Flagged rows (gap < GAP_T) recomputed by vq_rescue.
// ---------------------------------------------------------------------------
__global__ __launch_bounds__(512)
void vq_main(const float* __restrict__ z, const float* __restrict__ tgt,
             const unsigned short* __restrict__ cbp, const float* __restrict__ E,
             float* __restrict__ out, int* __restrict__ rlist,
             int* __restrict__ rcnt) {
    __shared__ alignas(16) unsigned char LDS[2][BM * KP * 2 * 2];  // 2 x 32 KB

    const int tid = threadIdx.x;
    const int r0  = blockIdx.x * BM;
    const int l   = tid & 63;
    const int wv  = tid >> 6;        // 0..7
    const int lr  = l & 15;
    const int lg  = l >> 4;

    f32x4 acc[2][4];
#pragma unroll
    for (int m = 0; m < 2; ++m)
#pragma unroll
        for (int nt = 0; nt < 4; ++nt) acc[m][nt] = (f32x4){0.f, 0.f, 0.f, 0.f};

    const int aswz = (lr & 7) << 4;
    const unsigned char* bbase = (const unsigned char*)cbp + l * 16;
#define BFRAG(fi) (*reinterpret_cast<const short8*>(bbase + (unsigned)(fi) * 1024u))

    // staging decomposition: thread covers rows row0+8c (c=0..3) at f4-col c4
    const int c4    = tid & 63;
    const int row0  = tid >> 6;          // 0..7
    const int swz_w = (row0 & 7) << 4;
    const float* zbase = z + (size_t)(r0 + row0) * D + c4 * 4;

    // prologue: panel 0 -> buf 0
    {
        float4 zn[4];
#pragma unroll
        for (int c = 0; c < 4; ++c)
            zn[c] = *reinterpret_cast<const float4*>(zbase + (size_t)(8 * c) * D);
#pragma unroll
        for (int c = 0; c < 4; ++c) {
            const int ad = ((row0 + 8 * c) * 512 + c4 * 8) ^ swz_w;
            cvt_write(zn[c], &LDS[0][ad], &LDS[0][16384 + ad]);
        }
    }

#pragma unroll 1
    for (int p = 0; p < 4; ++p) {
        __syncthreads();
        unsigned char* Ah  = &LDS[p & 1][0];
        unsigned char* Al  = Ah + 16384;
        unsigned char* Ahn = &LDS[(p + 1) & 1][0];

        // (a) issue next panel's global z loads early (T14)
        float4 zn[4];
        if (p < 3) {
#pragma unroll
            for (int c = 0; c < 4; ++c)
                zn[c] = *reinterpret_cast<const float4*>(
                    zbase + (size_t)(8 * c) * D + (p + 1) * KP);
        }

        // (b) MFMA: 8 k-steps of 32; B register pipeline one step ahead
        const int fp0 = (wv * 4 * 32 + p * 8) * 2;
        short8 b0[4][2], b1[4][2];
#pragma unroll
        for (int nt = 0; nt < 4; ++nt) {
            const int fi = fp0 + nt * 64;
            b0[nt][0] = BFRAG(fi + 0);
            b0[nt][1] = BFRAG(fi + 1);
        }
#pragma unroll 2
        for (int ks = 0; ks < 8; ++ks) {
            if (ks < 7) {
#pragma unroll
                for (int nt = 0; nt < 4; ++nt) {
                    const int fi = fp0 + nt * 64 + (ks + 1) * 2;
                    b1[nt][0] = BFRAG(fi + 0);
                    b1[nt][1] = BFRAG(fi + 1);
                }
            }
            short8 ah[2], al[2];
#pragma unroll
            for (int m = 0; m < 2; ++m) {
                const int ad = ((m * 16 + lr) * 512 + lg * 16 + ks * 64) ^ aswz;
                ah[m] = *reinterpret_cast<const short8*>(Ah + ad);
                al[m] = *reinterpret_cast<const short8*>(Al + ad);
            }
#pragma unroll
            for (int nt = 0; nt < 4; ++nt) {
                const short8 bh = b0[nt][0];
                const short8 bl = b0[nt][1];
#pragma unroll
                for (int m = 0; m < 2; ++m) {
                    acc[m][nt] = __builtin_amdgcn_mfma_f32_16x16x32_bf16(ah[m], bh, acc[m][nt], 0, 0, 0);
                    acc[m][nt] = __builtin_amdgcn_mfma_f32_16x16x32_bf16(ah[m], bl, acc[m][nt], 0, 0, 0);
                    acc[m][nt] = __builtin_amdgcn_mfma_f32_16x16x32_bf16(al[m], bh, acc[m][nt], 0, 0, 0);
                }
            }
#pragma unroll
            for (int nt = 0; nt < 4; ++nt) {
                b0[nt][0] = b1[nt][0];
                b0[nt][1] = b1[nt][1];
            }
        }

        // (c) convert + write next panel into the other buffer (VALU tail)
        if (p < 3) {
#pragma unroll
            for (int c = 0; c < 4; ++c) {
                const int ad = ((row0 + 8 * c) * 512 + c4 * 8) ^ swz_w;
                cvt_write(zn[c], Ahn + ad, Ahn + 16384 + ad);
            }
        }
    }
#undef BFRAG

    // ---- A-panels done: alias reduction arrays onto LDS[1] (post-barrier) --
    __syncthreads();
    float* cv1     = (float*)&LDS[1][0];       // [8][32]
    float* cv2     = (float*)&LDS[1][1024];    // [8][32]
    int*   ci1     = (int*)  &LDS[1][2048];    // [8][32]
    int*   bestk_s = (int*)  &LDS[1][3072];    // [32]

    // ---- top-2 per row: nt scan, 16-lane butterfly, wave merge ----
    // acc[m][nt][r] = logits[row = m*16 + lg*4 + r][code = wv*64 + nt*16 + lr]
#pragma unroll
    for (int m = 0; m < 2; ++m)
#pragma unroll
        for (int r = 0; r < 4; ++r) {
            float v1 = acc[m][0][r];
            int   i1 = wv * 64 + lr;
            float v2 = -INFINITY;
#pragma unroll
            for (int nt = 1; nt < 4; ++nt) {
                const float v = acc[m][nt][r];
                const int   n = wv * 64 + nt * 16 + lr;
                if (v > v1) { v2 = v1; v1 = v; i1 = n; }
                else        { v2 = fmaxf(v2, v); }
            }
#pragma unroll
            for (int msk = 1; msk < 16; msk <<= 1) {
                const float ov1 = __shfl_xor(v1, msk);
                const float ov2 = __shfl_xor(v2, msk);
                const int   oi1 = __shfl_xor(i1, msk);
                if (ov1 > v1 || (ov1 == v1 && oi1 < i1)) { v2 = fmaxf(v1, ov2); v1 = ov1; i1 = oi1; }
                else                                     { v2 = fmaxf(v2, ov1); }
            }
            if (lr == 0) {
                const int row = m * 16 + lg * 4 + r;
                cv1[wv * BM + row] = v1; cv2[wv * BM + row] = v2; ci1[wv * BM + row] = i1;
            }
        }
    __syncthreads();
    if (tid < BM) {
        float v1 = cv1[tid], v2 = cv2[tid];
        int   i1 = ci1[tid];
        for (int w = 1; w < 8; ++w) {
            const float a1 = cv1[w * BM + tid], a2 = cv2[w * BM + tid];
            const int   b1 = ci1[w * BM + tid];
            if (a1 > v1 || (a1 == v1 && b1 < i1)) { v2 = fmaxf(v1, a2); v1 = a1; i1 = b1; }
            else                                  { v2 = fmaxf(v2, a1); }
        }
        bestk_s[tid] = i1;
        if (v1 - v2 < GAP_T) {
            const int pos = atomicAdd(rcnt, 1);
            rlist[pos] = r0 + tid;
        }
    }
    __syncthreads();

    // ---- fused epilogue: out = target * (1 + E[best]) for the 32 rows ----
    const int erow = tid >> 4;           // 0..31
    const int ecol = tid & 15;           // float4 lane within 16-thread group
    const int bi   = bestk_s[erow];
    const float4* trow = reinterpret_cast<const float4*>(tgt + (size_t)(r0 + erow) * D);
    const float4* eptr = reinterpret_cast<const float4*>(E + (size_t)bi * D);
    float4*       orow = reinterpret_cast<float4*>(out + (size_t)(r0 + erow) * D);
#pragma unroll 4
    for (int it = 0; it < 16; ++it) {
        const int c = ecol + it * 16;    // 0..255
        const float4 tv = trow[c];
        const float4 ev = eptr[c];
        float4 o;
        o.x = tv.x * (1.0f + ev.x);
        o.y = tv.y * (1.0f + ev.y);
        o.z = tv.z * (1.0f + ev.z);
        o.w = tv.w * (1.0f + ev.w);
        orow[c] = o;
    }
}

// ---------------------------------------------------------------------------
// Kernel C: exact f32 rescue over the compacted row list (~160 rows).
// Transposed-codebook scan (coalesced, no per-iter cross-lane ops); rewrites
// the output row. Parallel across rows: grid 256, ~1 row per block.
// ---------------------------------------------------------------------------
__global__ __launch_bounds__(256)
void vq_rescue(const float* __restrict__ z, const float* __restrict__ cft,
               const float* __restrict__ tgt, const float* __restrict__ E,
               const int* __restrict__ rlist, const int* __restrict__ rcnt,
               float* __restrict__ out) {
    const int cnt = rcnt[0];
    const int tid = threadIdx.x;
    const int l   = tid & 63;
    const int wv  = tid >> 6;        // 0..3
    __shared__ float zs[D];
    __shared__ float wvv[4];
    __shared__ int   wvi[4];
    __shared__ int   bestsh;

    const float2* ct = reinterpret_cast<const float2*>(cft) + tid;  // [d][256 x float2]

    for (int i = blockIdx.x; i < cnt; i += gridDim.x) {
        const int row = rlist[i];
        __syncthreads();             // protect zs/wvv reuse across iterations
        reinterpret_cast<float4*>(zs)[tid] =
            reinterpret_cast<const float4*>(z + (size_t)row * D)[tid];
        __syncthreads();

        float s0 = 0.f, s1 = 0.f, t0 = 0.f, t1 = 0.f;
#pragma unroll 8
        for (int d = 0; d < D; d += 2) {
            const float2 va = ct[(size_t)d * 256];
            const float2 vb = ct[(size_t)(d + 1) * 256];
            const float  a  = zs[d];
            const float  b  = zs[d + 1];
            s0 = fmaf(a, va.x, s0); s1 = fmaf(a, va.y, s1);
            t0 = fmaf(b, vb.x, t0); t1 = fmaf(b, vb.y, t1);
        }
        s0 += t0; s1 += t1;

        float bv; int bi;
        if (s1 > s0) { bv = s1; bi = tid * 2 + 1; }
        else         { bv = s0; bi = tid * 2; }      // tie -> lower index
#pragma unroll
        for (int off = 32; off > 0; off >>= 1) {
            const float ov = __shfl_down(bv, off);
            const int   oi = __shfl_down(bi, off);
            if (ov > bv || (ov == bv && oi < bi)) { bv = ov; bi = oi; }
        }
        if (l == 0) { wvv[wv] = bv; wvi[wv] = bi; }
        __syncthreads();
        if (tid == 0) {
            float fv = wvv[0]; int fi = wvi[0];
            for (int w = 1; w < 4; ++w)
                if (wvv[w] > fv || (wvv[w] == fv && wvi[w] < fi)) { fv = wvv[w]; fi = wvi[w]; }
            bestsh = fi;
        }
        __syncthreads();
        const int best = bestsh;

        const float4 tv = reinterpret_cast<const float4*>(tgt + (size_t)row * D)[tid];
        const float4 ev = reinterpret_cast<const float4*>(E + (size_t)best * D)[tid];
        float4 o;
        o.x = tv.x * (1.0f + ev.x);
        o.y = tv.y * (1.0f + ev.y);
        o.z = tv.z * (1.0f + ev.z);
        o.w = tv.w * (1.0f + ev.w);
        reinterpret_cast<float4*>(out + (size_t)row * D)[tid] = o;
    }
}

extern "C" void kernel_launch(void* const* d_in, const int* in_sizes, int n_in,
                              void* d_out, int out_size, void* d_ws, size_t ws_size,
                              hipStream_t stream) {
    const float* z        = (const float*)d_in[0];
    const float* target   = (const float*)d_in[1];
    const float* codebook = (const float*)d_in[2];
    const float* E        = (const float*)d_in[3];
    float* out = (float*)d_out;

    unsigned short* cbp   = (unsigned short*)d_ws;              // 2 MB packed hi/lo
    float*          cft   = (float*)(cbp + (size_t)K * D * 2);  // 2 MB f32 transposed
    int*            rlist = (int*)(cft + (size_t)K * D);        // 64 KB
    int*            rcnt  = rlist + ROWS;                       // 4 B

    const int rows = in_sizes[0] / D;                           // 16384
    hipLaunchKernelGGL(prep_codebook, dim3(K), dim3(256), 0, stream,
                       codebook, cbp, cft, rcnt);
    hipLaunchKernelGGL(vq_main, dim3(rows / BM), dim3(512), 0, stream,
                       z, target, cbp, E, out, rlist, rcnt);
    hipLaunchKernelGGL(vq_rescue, dim3(256), dim3(256), 0, stream,
                       z, cft, target, E, rlist, rcnt, out);
}